// Round 1
// baseline (63.551 us; speedup 1.0000x reference)
//
#include <hip/hip_runtime.h>
#include <math.h>

constexpr int BATCH = 4;
constexpr int NPTS  = 8192;            // points per batch, both clouds
constexpr int BLOCK = 256;
constexpr int PTS_PER_THREAD = 4;      // own points per thread
constexpr int OWN_TILE   = BLOCK * PTS_PER_THREAD;  // 1024
constexpr int OTHER_TILE = 1024;                    // other-cloud chunk staged in LDS
constexpr int GROUPS = NPTS / OWN_TILE;             // 8
constexpr int CHUNKS = NPTS / OTHER_TILE;           // 8
constexpr int BLOCKS_PER_DIR = BATCH * GROUPS * CHUNKS; // 256
constexpr int CLOUD = BATCH * NPTS;                 // 32768 points per cloud

// ---------------------------------------------------------------- init: +inf
__global__ void cd_init(unsigned int* __restrict__ w, int n) {
    int i = blockIdx.x * blockDim.x + threadIdx.x;
    if (i < n) w[i] = 0x7F800000u;  // +inf bit pattern
}

// ------------------------------------------------- main: per-chunk min pass
// dir 0: own = xyz1, other = xyz2 (computes dist1 partial mins)
// dir 1: own = xyz2, other = xyz1 (computes dist2 partial mins)
__global__ __launch_bounds__(BLOCK) void cd_min(
    const float* __restrict__ xyz1, const float* __restrict__ xyz2,
    unsigned int* __restrict__ dmin /* [2 * CLOUD] */) {

    const int bid = blockIdx.x;
    const int dir = bid >> 8;       // BLOCKS_PER_DIR == 256
    const int lb  = bid & 255;
    const int b   = lb >> 6;        // batch (4)
    const int rem = lb & 63;
    const int grp = rem >> 3;       // own group (8)
    const int chk = rem & 7;        // other chunk (8)

    const float* own = dir ? xyz2 : xyz1;
    const float* oth = dir ? xyz1 : xyz2;
    unsigned int* dptr = dmin + dir * CLOUD;

    const int ownBase = b * NPTS + grp * OWN_TILE;
    const int othBase = b * NPTS + chk * OTHER_TILE;

    __shared__ float4 tile[OTHER_TILE];  // (x, y, z, |p|^2) — 16 KB

    const int t = threadIdx.x;

    // ---- stage other chunk: thread t handles 4 consecutive points (12 floats)
    {
        const float4* src =
            reinterpret_cast<const float4*>(oth + (size_t)othBase * 3) + t * 3;
        float4 a = src[0], q = src[1], c = src[2];
        // p0=(a.x,a.y,a.z) p1=(a.w,q.x,q.y) p2=(q.z,q.w,c.x) p3=(c.y,c.z,c.w)
        tile[t * 4 + 0] = make_float4(a.x, a.y, a.z, a.x*a.x + a.y*a.y + a.z*a.z);
        tile[t * 4 + 1] = make_float4(a.w, q.x, q.y, a.w*a.w + q.x*q.x + q.y*q.y);
        tile[t * 4 + 2] = make_float4(q.z, q.w, c.x, q.z*q.z + q.w*q.w + c.x*c.x);
        tile[t * 4 + 3] = make_float4(c.y, c.z, c.w, c.y*c.y + c.z*c.z + c.w*c.w);
    }

    // ---- own points: 4 per thread, consecutive
    float nx[4], ny[4], nz[4], rr[4], mv[4];
    {
        const float4* src =
            reinterpret_cast<const float4*>(own + (size_t)ownBase * 3) + t * 3;
        float4 a = src[0], q = src[1], c = src[2];
        const float px[4] = {a.x, a.w, q.z, c.y};
        const float py[4] = {a.y, q.x, q.w, c.z};
        const float pz[4] = {a.z, q.y, c.x, c.w};
#pragma unroll
        for (int p = 0; p < 4; ++p) {
            nx[p] = -2.0f * px[p];
            ny[p] = -2.0f * py[p];
            nz[p] = -2.0f * pz[p];
            rr[p] = px[p]*px[p] + py[p]*py[p] + pz[p]*pz[p];
            mv[p] = INFINITY;
        }
    }
    __syncthreads();

    // ---- scan chunk: per other-point, 4 own distances (3 FMA + 1 min each)
#pragma unroll 4
    for (int j = 0; j < OTHER_TILE; ++j) {
        const float4 q = tile[j];  // broadcast ds_read_b128, uniform addr
#pragma unroll
        for (int p = 0; p < 4; ++p) {
            float v = fmaf(nx[p], q.x, q.w);
            v = fmaf(ny[p], q.y, v);
            v = fmaf(nz[p], q.z, v);
            mv[p] = fminf(mv[p], v);
        }
    }

    // ---- publish: d = max(r1 + min, 0); uint atomicMin is exact (d >= 0)
#pragma unroll
    for (int p = 0; p < 4; ++p) {
        float d = fmaxf(rr[p] + mv[p], 0.0f);
        atomicMin(&dptr[ownBase + t * PTS_PER_THREAD + p], __float_as_uint(d));
    }
}

// ------------------------------------------ final: deterministic sum + means
__global__ __launch_bounds__(1024) void cd_reduce(
    const unsigned int* __restrict__ dmin, float* __restrict__ out) {
    __shared__ float s1[16], s2[16];
    const int t = threadIdx.x;
    float a = 0.0f, c = 0.0f;
    for (int i = t; i < CLOUD; i += 1024) {
        a += __uint_as_float(dmin[i]);
        c += __uint_as_float(dmin[CLOUD + i]);
    }
#pragma unroll
    for (int off = 32; off > 0; off >>= 1) {
        a += __shfl_down(a, off, 64);
        c += __shfl_down(c, off, 64);
    }
    const int wave = t >> 6;
    if ((t & 63) == 0) { s1[wave] = a; s2[wave] = c; }
    __syncthreads();
    if (t == 0) {
        float ta = 0.0f, tc = 0.0f;
#pragma unroll
        for (int w = 0; w < 16; ++w) { ta += s1[w]; tc += s2[w]; }
        out[0] = ta / (float)CLOUD + tc / (float)CLOUD;
    }
}

extern "C" void kernel_launch(void* const* d_in, const int* in_sizes, int n_in,
                              void* d_out, int out_size, void* d_ws, size_t ws_size,
                              hipStream_t stream) {
    const float* xyz1 = (const float*)d_in[0];
    const float* xyz2 = (const float*)d_in[1];
    unsigned int* dmin = (unsigned int*)d_ws;   // 2 * 32768 uints = 256 KB
    float* out = (float*)d_out;

    cd_init<<<(2 * CLOUD + 255) / 256, 256, 0, stream>>>(dmin, 2 * CLOUD);
    cd_min<<<2 * BLOCKS_PER_DIR, BLOCK, 0, stream>>>(xyz1, xyz2, dmin);
    cd_reduce<<<1, 1024, 0, stream>>>(dmin, out);
}